// Round 1
// baseline (147.261 us; speedup 1.0000x reference)
//
#include <hip/hip_runtime.h>
#include <hip/hip_bf16.h>

#define BB 4
#define NN 4096
#define EE 65536
#define FIN 128
#define FOUT 64

// order-preserving float->uint encoding (monotonic for atomicMax on unsigned)
__device__ __forceinline__ unsigned enc_f32(float f) {
    unsigned b = __float_as_uint(f);
    return (b & 0x80000000u) ? ~b : (b | 0x80000000u);
}
__device__ __forceinline__ float dec_f32(unsigned e) {
    unsigned b = (e & 0x80000000u) ? (e & 0x7FFFFFFFu) : ~e;
    return __uint_as_float(b);
}

// Wh[b,n,f] = sum_k h[b,n,k] * W[k,f].  256 threads = 4 rows x 64 cols.
__global__ void wh_kernel(const float* __restrict__ h, const float* __restrict__ W,
                          float* __restrict__ Wh) {
    __shared__ float Ws[FIN][FOUT];   // 32 KiB
    int tid = threadIdx.x;
    for (int i = tid; i < FIN * FOUT; i += 256) Ws[i / FOUT][i % FOUT] = W[i];
    __syncthreads();
    int f = tid & 63;
    int ry = tid >> 6;
    long row = (long)blockIdx.x * 4 + ry;       // 0..BB*NN-1
    const float* hr = h + row * FIN;
    float acc = 0.f;
#pragma unroll
    for (int k = 0; k < FIN; ++k) acc += hr[k] * Ws[k][f];
    Wh[row * FOUT + f] = acc;
}

// as[n] = dot(Wh0[n], a[0:64]); at[n] = dot(Wh0[n], a[64:128])
__global__ void attn_coef_kernel(const float* __restrict__ Wh, const float* __restrict__ a,
                                 float* __restrict__ as_, float* __restrict__ at_) {
    int tid = threadIdx.x;
    int f = tid & 63, w = tid >> 6;
    int n = blockIdx.x * 4 + w;
    float v = Wh[(long)n * FOUT + f];           // batch-0 rows
    float ps = v * a[f];
    float pt = v * a[64 + f];
    for (int off = 32; off; off >>= 1) {
        ps += __shfl_down(ps, off);
        pt += __shfl_down(pt, off);
    }
    if (f == 0) { as_[n] = ps; at_[n] = pt; }
}

// per-column max of as[s] over positive edges (dup-insensitive)
__global__ void pass1_kernel(const int* __restrict__ ei, const float* __restrict__ as_,
                             const float* __restrict__ at_, unsigned* __restrict__ Menc) {
    int idx = blockIdx.x * 256 + threadIdx.x;
    if (idx >= BB * EE) return;
    int b = idx / EE, j = idx % EE;
    const int* eb = ei + (long)b * 2 * EE;
    int s = eb[j], t = eb[EE + j];
    float as_s = as_[s];
    float e = as_s + at_[t];
    if (e > 0.f) atomicMax(&Menc[b * NN + t], enc_f32(as_s));
}

// softmax denominator over DISTINCT positive edges (bitmap dedup)
__global__ void pass2_kernel(const int* __restrict__ ei, const float* __restrict__ as_,
                             const float* __restrict__ at_, const unsigned* __restrict__ Menc,
                             unsigned* __restrict__ bitmap, float* __restrict__ D) {
    int idx = blockIdx.x * 256 + threadIdx.x;
    if (idx >= BB * EE) return;
    int b = idx / EE, j = idx % EE;
    const int* eb = ei + (long)b * 2 * EE;
    int s = eb[j], t = eb[EE + j];
    float as_s = as_[s];
    float e = as_s + at_[t];
    if (e > 0.f) {
        long bit = (long)s * NN + t;
        unsigned* wp = bitmap + (long)b * ((long)NN * NN / 32) + (bit >> 5);
        unsigned m = 1u << (bit & 31);
        unsigned old = atomicOr(wp, m);
        if (!(old & m)) {
            float Mas = dec_f32(Menc[b * NN + t]);
            atomicAdd(&D[b * NN + t], expf(as_s - Mas));
        }
    }
}

// base[b,f] = (1/N) * sum over columns with NO positive edge of Wh[b,t,f]
__global__ void base_kernel(const unsigned* __restrict__ Menc, const float* __restrict__ Wh,
                            float* __restrict__ base) {
    int bx = blockIdx.x;                 // BB*32 blocks
    int b = bx >> 5, chunk = bx & 31;
    int f = threadIdx.x & 63, ty = threadIdx.x >> 6;
    float acc = 0.f;
    int t0 = chunk * (NN / 32);
    for (int t = t0 + ty; t < t0 + NN / 32; t += 4) {
        if (Menc[b * NN + t] == 0u) acc += Wh[((long)b * NN + t) * FOUT + f];
    }
    __shared__ float red[4][64];
    red[ty][f] = acc;
    __syncthreads();
    if (ty == 0) {
        float s = red[0][f] + red[1][f] + red[2][f] + red[3][f];
        if (s != 0.f) atomicAdd(&base[b * FOUT + f], s * (1.0f / NN));
        else if (s != 0.f) {} // keep structure simple
        if (s == 0.f) atomicAdd(&base[b * FOUT + f], 0.f); // uniform path (cheap, keeps determinism simple)
    }
}

// sparse scatter: acc[b,s,:] += w(s,t) * Wh[b,t,:], one 64-lane wave per edge
__global__ void pass3_kernel(const int* __restrict__ ei, const float* __restrict__ as_,
                             const float* __restrict__ at_, const unsigned* __restrict__ Menc,
                             const float* __restrict__ D, const float* __restrict__ Wh,
                             unsigned* __restrict__ bitmap, float* __restrict__ acc) {
    int tid = threadIdx.x;
    int lane = tid & 63;
    int widx = blockIdx.x * 4 + (tid >> 6);    // edge id
    if (widx >= BB * EE) return;
    int b = widx / EE, j = widx % EE;
    const int* eb = ei + (long)b * 2 * EE;
    int s = eb[j], t = eb[EE + j];
    float as_s = as_[s];
    float e = as_s + at_[t];
    if (e <= 0.f) return;                       // wave-uniform
    float w = 0.f;
    if (lane == 0) {
        long bit = (long)s * NN + t;
        unsigned* wp = bitmap + (long)b * ((long)NN * NN / 32) + (bit >> 5);
        unsigned m = 1u << (bit & 31);
        unsigned old = atomicOr(wp, m);
        if (!(old & m)) {
            float Mas = dec_f32(Menc[b * NN + t]);
            w = expf(as_s - Mas) / D[b * NN + t];
        }
    }
    w = __shfl(w, 0);
    if (w != 0.f) {
        atomicAdd(&acc[((long)b * NN + s) * FOUT + lane],
                  w * Wh[((long)b * NN + t) * FOUT + lane]);
    }
}

// out = ELU(acc + base)
__global__ void elu_kernel(const float* __restrict__ acc, const float* __restrict__ base,
                           float* __restrict__ out) {
    long idx = (long)blockIdx.x * 256 + threadIdx.x;
    int f = (int)(idx & 63);
    long bn = idx >> 6;
    int b = (int)(bn >> 12);                    // NN = 4096
    float x = acc[idx] + base[b * FOUT + f];
    out[idx] = x > 0.f ? x : expm1f(x);
}

extern "C" void kernel_launch(void* const* d_in, const int* in_sizes, int n_in,
                              void* d_out, int out_size, void* d_ws, size_t ws_size,
                              hipStream_t stream) {
    const float* h  = (const float*)d_in[0];
    const int*   ei = (const int*)d_in[1];
    const float* W  = (const float*)d_in[2];
    const float* a  = (const float*)d_in[3];
    float* out = (float*)d_out;

    char* ws = (char*)d_ws;
    float*    Wh     = (float*)(ws);                          // 4 MiB
    float*    acc    = (float*)(ws + 4194304);                // 4 MiB
    unsigned* bitmap = (unsigned*)(ws + 8388608);             // 8 MiB
    unsigned* Menc   = (unsigned*)(ws + 16777216);            // 64 KiB
    float*    D      = (float*)(ws + 16842752);               // 64 KiB
    float*    as_    = (float*)(ws + 16908288);               // 16 KiB
    float*    at_    = (float*)(ws + 16924672);               // 16 KiB
    float*    base   = (float*)(ws + 16941056);               // 1 KiB

    // zero: Menc + D + (as,at not needed) ... Menc,D,base contiguous-ish: do pieces
    hipMemsetAsync(Menc, 0, 65536 + 65536, stream);           // Menc + D
    hipMemsetAsync(base, 0, BB * FOUT * sizeof(float), stream);
    hipMemsetAsync(acc, 0, 4194304, stream);

    wh_kernel<<<BB * NN / 4, 256, 0, stream>>>(h, W, Wh);
    attn_coef_kernel<<<NN / 4, 256, 0, stream>>>(Wh, a, as_, at_);
    pass1_kernel<<<(BB * EE) / 256, 256, 0, stream>>>(ei, as_, at_, Menc);

    hipMemsetAsync(bitmap, 0, 8388608, stream);
    pass2_kernel<<<(BB * EE) / 256, 256, 0, stream>>>(ei, as_, at_, Menc, bitmap, D);
    base_kernel<<<BB * 32, 256, 0, stream>>>(Menc, Wh, base);

    hipMemsetAsync(bitmap, 0, 8388608, stream);
    pass3_kernel<<<(BB * EE) / 4, 256, 0, stream>>>(ei, as_, at_, Menc, D, Wh, bitmap, acc);

    elu_kernel<<<(BB * NN * FOUT) / 256, 256, 0, stream>>>(acc, base, out);
}

// Round 2
// 88.454 us; speedup vs baseline: 1.6648x; 1.6648x over previous
//
#include <hip/hip_runtime.h>
#include <hip/hip_bf16.h>

#define BB 4
#define NN 4096
#define EE 65536
#define FIN 128
#define FOUT 64
#define CAP 64

// order-preserving float->uint encoding (monotonic for atomicMax on unsigned)
__device__ __forceinline__ unsigned enc_f32(float f) {
    unsigned b = __float_as_uint(f);
    return (b & 0x80000000u) ? ~b : (b | 0x80000000u);
}
__device__ __forceinline__ float dec_f32(unsigned e) {
    unsigned b = (e & 0x80000000u) ? (e & 0x7FFFFFFFu) : ~e;
    return __uint_as_float(b);
}

// Wh = h @ W : register-tiled 32-row x 64-col block, 2x4 outputs/thread.
__global__ __launch_bounds__(256) void wh_kernel(const float* __restrict__ h,
                                                 const float* __restrict__ W,
                                                 float* __restrict__ Wh) {
    __shared__ float hs[32][132];    // +4 pad breaks bank aliasing
    __shared__ float Ws[128][64];
    int tid = threadIdx.x;
    long row0 = (long)blockIdx.x * 32;
    for (int i = tid; i < 2048; i += 256) {          // W: 128x64 floats
        float4 v = ((const float4*)W)[i];
        int k = (i * 4) >> 6, c = (i * 4) & 63;
        *(float4*)&Ws[k][c] = v;
    }
    for (int i = tid; i < 1024; i += 256) {          // h: 32x128 floats
        float4 v = ((const float4*)(h + row0 * FIN))[i];
        int r = (i * 4) >> 7, c = (i * 4) & 127;
        *(float4*)&hs[r][c] = v;
    }
    __syncthreads();
    int tx = tid & 15, ty = tid >> 4;
    int c0 = tx * 4, r0 = ty * 2;
    float acc[2][4] = {};
#pragma unroll
    for (int k = 0; k < 128; k += 4) {
        float4 w0 = *(const float4*)&Ws[k][c0];
        float4 w1 = *(const float4*)&Ws[k + 1][c0];
        float4 w2 = *(const float4*)&Ws[k + 2][c0];
        float4 w3 = *(const float4*)&Ws[k + 3][c0];
#pragma unroll
        for (int r = 0; r < 2; ++r) {
            float4 hv = *(const float4*)&hs[r0 + r][k];
            acc[r][0] += hv.x * w0.x + hv.y * w1.x + hv.z * w2.x + hv.w * w3.x;
            acc[r][1] += hv.x * w0.y + hv.y * w1.y + hv.z * w2.y + hv.w * w3.y;
            acc[r][2] += hv.x * w0.z + hv.y * w1.z + hv.z * w2.z + hv.w * w3.z;
            acc[r][3] += hv.x * w0.w + hv.y * w1.w + hv.z * w2.w + hv.w * w3.w;
        }
    }
#pragma unroll
    for (int r = 0; r < 2; ++r)
        *(float4*)&Wh[(row0 + r0 + r) * FOUT + c0] = *(float4*)&acc[r][0];
}

// as[n] = dot(Wh0[n], a[0:64]); at[n] = dot(Wh0[n], a[64:128])
__global__ void attn_coef_kernel(const float* __restrict__ Wh, const float* __restrict__ a,
                                 float* __restrict__ as_, float* __restrict__ at_) {
    int tid = threadIdx.x;
    int f = tid & 63, w = tid >> 6;
    int n = blockIdx.x * 4 + w;
    float v = Wh[(long)n * FOUT + f];           // batch-0 rows
    float ps = v * a[f];
    float pt = v * a[64 + f];
    for (int off = 32; off; off >>= 1) {
        ps += __shfl_down(ps, off);
        pt += __shfl_down(pt, off);
    }
    if (f == 0) { as_[n] = ps; at_[n] = pt; }
}

// ONE pass over all edges: dedup (bitmap), build per-source CSR, column max M.
__global__ void edge_kernel(const int* __restrict__ ei, const float* __restrict__ as_,
                            const float* __restrict__ at_, unsigned* __restrict__ bitmap,
                            unsigned* __restrict__ Menc, int* __restrict__ deg,
                            int* __restrict__ csr) {
    int idx = blockIdx.x * 256 + threadIdx.x;
    int b = idx >> 16;                 // EE = 65536
    int j = idx & 65535;
    const int* eb = ei + (long)b * 2 * EE;
    int s = eb[j], t = eb[EE + j];
    float as_s = as_[s];
    float e = as_s + at_[t];
    if (e > 0.f) {
        int row = (b << 12) | s;                       // b*NN + s
        long bit = ((long)row << 12) | t;              // global bit index
        unsigned m = 1u << (t & 31);
        unsigned old = atomicOr(&bitmap[bit >> 5], m);
        if (!(old & m)) {                              // first time for (b,s,t)
            atomicMax(&Menc[(b << 12) | t], enc_f32(as_s));
            int slot = atomicAdd(&deg[row], 1);
            if (slot < CAP) csr[row * CAP + slot] = t;
        }
    }
}

// D[b,t] += exp(as[s] - M_t) over distinct positive edges (via CSR)
__global__ void denom_kernel(const int* __restrict__ deg, const int* __restrict__ csr,
                             const float* __restrict__ as_, const unsigned* __restrict__ Menc,
                             float* __restrict__ D) {
    int tid = threadIdx.x;
    int lane = tid & 63;
    int row = blockIdx.x * 4 + (tid >> 6);
    int b = row >> 12, s = row & 4095;
    int d = min(deg[row], CAP);
    float as_s = as_[s];
    for (int j = lane; j < d; j += 64) {
        int t = csr[row * CAP + j];
        float M = dec_f32(Menc[(b << 12) | t]);
        atomicAdd(&D[(b << 12) | t], expf(as_s - M));
    }
}

// g[b,t] = exp(-M_t)/D_t  (0 if column has no positive edge)
__global__ void gcoef_kernel(const unsigned* __restrict__ Menc, const float* __restrict__ D,
                             float* __restrict__ g) {
    int i = blockIdx.x * 256 + threadIdx.x;
    unsigned m = Menc[i];
    g[i] = m ? expf(-dec_f32(m)) / D[i] : 0.f;
}

// base[b,f] = (1/N) * sum over columns with NO positive edge of Wh[b,t,f]
__global__ void base_kernel(const unsigned* __restrict__ Menc, const float* __restrict__ Wh,
                            float* __restrict__ base) {
    int bx = blockIdx.x;                 // BB*32 blocks
    int b = bx >> 5, chunk = bx & 31;
    int f = threadIdx.x & 63, ty = threadIdx.x >> 6;
    float acc = 0.f;
    int t0 = chunk * (NN / 32);
    for (int t = t0 + ty; t < t0 + NN / 32; t += 4)
        if (Menc[(b << 12) | t] == 0u) acc += Wh[(((long)b << 12) | t) * FOUT + f];
    __shared__ float red[4][64];
    red[ty][f] = acc;
    __syncthreads();
    if (ty == 0)
        atomicAdd(&base[(b << 6) | f],
                  (red[0][f] + red[1][f] + red[2][f] + red[3][f]) * (1.0f / NN));
}

// one wave per output row: out[b,s,:] = ELU( exp(as_s) * sum_t g[b,t]*Wh[b,t,:] + base )
__global__ void gather_kernel(const int* __restrict__ deg, const int* __restrict__ csr,
                              const float* __restrict__ as_, const float* __restrict__ g,
                              const float* __restrict__ Wh, const float* __restrict__ base,
                              float* __restrict__ out) {
    int tid = threadIdx.x;
    int lane = tid & 63;
    int row = blockIdx.x * 4 + (tid >> 6);
    int b = row >> 12, s = row & 4095;
    int d = min(deg[row], CAP);
    float Es = expf(as_[s]);
    float acc = 0.f;
    const int* cr = csr + row * CAP;
    const float* Whb = Wh + (((long)b << 12) * FOUT);
    for (int j = 0; j < d; ++j) {
        int t = cr[j];                      // wave-uniform broadcast load
        float w = g[(b << 12) | t];
        acc += w * Whb[t * FOUT + lane];    // coalesced 256B gather
    }
    float x = Es * acc + base[(b << 6) | lane];
    out[(long)row * FOUT + lane] = x > 0.f ? x : expm1f(x);
}

extern "C" void kernel_launch(void* const* d_in, const int* in_sizes, int n_in,
                              void* d_out, int out_size, void* d_ws, size_t ws_size,
                              hipStream_t stream) {
    const float* h  = (const float*)d_in[0];
    const int*   ei = (const int*)d_in[1];
    const float* W  = (const float*)d_in[2];
    const float* a  = (const float*)d_in[3];
    float* out = (float*)d_out;

    char* ws = (char*)d_ws;
    float*    Wh     = (float*)(ws);                       // 4 MiB
    unsigned* bitmap = (unsigned*)(ws + 4194304);          // 8 MiB
    int*      csr    = (int*)(ws + 12582912);              // 4 MiB (CAP=64)
    int*      deg    = (int*)(ws + 16777216);              // 64 KiB
    unsigned* Menc   = (unsigned*)(ws + 16842752);         // 64 KiB
    float*    D      = (float*)(ws + 16908288);            // 64 KiB
    float*    g      = (float*)(ws + 16973824);            // 64 KiB
    float*    as_    = (float*)(ws + 17039360);            // 16 KiB
    float*    at_    = (float*)(ws + 17055744);            // 16 KiB
    float*    base   = (float*)(ws + 17072128);            // 1 KiB

    hipMemsetAsync(bitmap, 0, 8388608, stream);
    hipMemsetAsync(deg, 0, 65536 * 3, stream);             // deg + Menc + D (contiguous)
    hipMemsetAsync(base, 0, BB * FOUT * sizeof(float), stream);

    wh_kernel<<<BB * NN / 32, 256, 0, stream>>>(h, W, Wh);
    attn_coef_kernel<<<NN / 4, 256, 0, stream>>>(Wh, a, as_, at_);
    edge_kernel<<<(BB * EE) / 256, 256, 0, stream>>>(ei, as_, at_, bitmap, Menc, deg, csr);
    denom_kernel<<<(BB * NN) / 4, 256, 0, stream>>>(deg, csr, as_, Menc, D);
    gcoef_kernel<<<(BB * NN) / 256, 256, 0, stream>>>(Menc, D, g);
    base_kernel<<<BB * 32, 256, 0, stream>>>(Menc, Wh, base);
    gather_kernel<<<(BB * NN) / 4, 256, 0, stream>>>(deg, csr, as_, g, Wh, base, out);
}

// Round 3
// 79.474 us; speedup vs baseline: 1.8529x; 1.1130x over previous
//
#include <hip/hip_runtime.h>
#include <hip/hip_bf16.h>

#define BB 4
#define NN 4096
#define EE 65536
#define FIN 128
#define FOUT 64
#define CAP 64

// order-preserving float->uint encoding (monotonic for atomicMax on unsigned)
__device__ __forceinline__ unsigned enc_f32(float f) {
    unsigned b = __float_as_uint(f);
    return (b & 0x80000000u) ? ~b : (b | 0x80000000u);
}
__device__ __forceinline__ float dec_f32(unsigned e) {
    unsigned b = (e & 0x80000000u) ? (e & 0x7FFFFFFFu) : ~e;
    return __uint_as_float(b);
}

// Zero deg/Menc/D/base (193 KiB) and compute Wa1[k]=sum_f W[k][f]a[f], Wa2 likewise.
// grid = 64 blocks x 256
__global__ void init_kernel(const float* __restrict__ W, const float* __restrict__ a,
                            int* __restrict__ deg, unsigned* __restrict__ Menc,
                            float* __restrict__ D, float* __restrict__ base,
                            float* __restrict__ Wa) {
    int tid = threadIdx.x;
    int gid = blockIdx.x * 256 + tid;           // 0..16383
    deg[gid] = 0;
    Menc[gid] = 0u;
    D[gid] = 0.f;
    if (gid < BB * FOUT) base[gid] = 0.f;
    if (blockIdx.x == 0) {                       // 256 threads: Wa1 (k=0..127), Wa2
        int half = tid >> 7, k = tid & 127;
        const float* wr = W + k * FOUT;
        const float* av = a + half * FOUT;
        float s = 0.f;
#pragma unroll 16
        for (int f = 0; f < FOUT; ++f) s += wr[f] * av[f];
        Wa[half * 128 + k] = s;
    }
}

// as[n] = h0[n].Wa1 ; at[n] = h0[n].Wa2  (batch-0 rows only). 1 wave per row.
__global__ void as_at_kernel(const float* __restrict__ h, const float* __restrict__ Wa,
                             float* __restrict__ as_, float* __restrict__ at_) {
    int tid = threadIdx.x;
    int lane = tid & 63;
    int n = blockIdx.x * 4 + (tid >> 6);
    float h0v = h[(long)n * FIN + lane];
    float h1v = h[(long)n * FIN + 64 + lane];
    float ps = h0v * Wa[lane] + h1v * Wa[64 + lane];
    float pt = h0v * Wa[128 + lane] + h1v * Wa[192 + lane];
    for (int off = 32; off; off >>= 1) {
        ps += __shfl_down(ps, off);
        pt += __shfl_down(pt, off);
    }
    if (lane == 0) { as_[n] = ps; at_[n] = pt; }
}

// Wh = h @ W : register-tiled 32-row x 64-col block, 2x4 outputs/thread.
__global__ __launch_bounds__(256) void wh_kernel(const float* __restrict__ h,
                                                 const float* __restrict__ W,
                                                 float* __restrict__ Wh) {
    __shared__ float hs[32][132];    // +4 pad breaks bank aliasing
    __shared__ float Ws[128][64];
    int tid = threadIdx.x;
    long row0 = (long)blockIdx.x * 32;
    for (int i = tid; i < 2048; i += 256) {          // W: 128x64 floats
        float4 v = ((const float4*)W)[i];
        int k = (i * 4) >> 6, c = (i * 4) & 63;
        *(float4*)&Ws[k][c] = v;
    }
    for (int i = tid; i < 1024; i += 256) {          // h: 32x128 floats
        float4 v = ((const float4*)(h + row0 * FIN))[i];
        int r = (i * 4) >> 7, c = (i * 4) & 127;
        *(float4*)&hs[r][c] = v;
    }
    __syncthreads();
    int tx = tid & 15, ty = tid >> 4;
    int c0 = tx * 4, r0 = ty * 2;
    float acc[2][4] = {};
#pragma unroll
    for (int k = 0; k < 128; k += 4) {
        float4 w0 = *(const float4*)&Ws[k][c0];
        float4 w1 = *(const float4*)&Ws[k + 1][c0];
        float4 w2 = *(const float4*)&Ws[k + 2][c0];
        float4 w3 = *(const float4*)&Ws[k + 3][c0];
#pragma unroll
        for (int r = 0; r < 2; ++r) {
            float4 hv = *(const float4*)&hs[r0 + r][k];
            acc[r][0] += hv.x * w0.x + hv.y * w1.x + hv.z * w2.x + hv.w * w3.x;
            acc[r][1] += hv.x * w0.y + hv.y * w1.y + hv.z * w2.y + hv.w * w3.y;
            acc[r][2] += hv.x * w0.z + hv.y * w1.z + hv.z * w2.z + hv.w * w3.z;
            acc[r][3] += hv.x * w0.w + hv.y * w1.w + hv.z * w2.w + hv.w * w3.w;
        }
    }
#pragma unroll
    for (int r = 0; r < 2; ++r)
        *(float4*)&Wh[(row0 + r0 + r) * FOUT + c0] = *(float4*)&acc[r][0];
}

// ONE pass over all edges: per-source CSR (with duplicates), column max M.
__global__ void edge_kernel(const int* __restrict__ ei, const float* __restrict__ as_,
                            const float* __restrict__ at_, unsigned* __restrict__ Menc,
                            int* __restrict__ deg, int* __restrict__ csr) {
    int idx = blockIdx.x * 256 + threadIdx.x;
    int b = idx >> 16;                 // EE = 65536
    int j = idx & 65535;
    const int* eb = ei + (long)b * 2 * EE;
    int s = eb[j], t = eb[EE + j];
    float as_s = as_[s];
    float e = as_s + at_[t];
    if (e > 0.f) {
        int row = (b << 12) | s;                       // b*NN + s
        atomicMax(&Menc[(b << 12) | t], enc_f32(as_s));
        int slot = atomicAdd(&deg[row], 1);
        if (slot < CAP) csr[row * CAP + slot] = t;
    }
}

// per-row in-wave dedup (shfl O(d^2) + ballot compact), then D[b,t] += exp(as_s - M_t)
__global__ void dedup_denom_kernel(int* __restrict__ deg, int* __restrict__ csr,
                                   const float* __restrict__ as_,
                                   const unsigned* __restrict__ Menc,
                                   float* __restrict__ D) {
    int tid = threadIdx.x;
    int lane = tid & 63;
    int row = blockIdx.x * 4 + (tid >> 6);
    int b = row >> 12, s = row & 4095;
    int draw = min(deg[row], CAP);                 // wave-uniform
    int t = -1;
    if (lane < draw) t = csr[row * CAP + lane];
    bool dup = false;
    for (int k = 0; k < draw; ++k) {
        int tk = __shfl(t, k);
        if (k < lane && tk == t) dup = true;
    }
    bool keep = (lane < draw) && !dup;
    unsigned long long mask = __ballot(keep);
    int pfx = __popcll(mask & ((1ull << lane) - 1ull));
    if (keep) {
        csr[row * CAP + pfx] = t;                  // compact in place (reads already done)
        float M = dec_f32(Menc[(b << 12) | t]);
        atomicAdd(&D[(b << 12) | t], expf(as_[s] - M));
    }
    if (lane == 0) deg[row] = __popcll(mask);
}

// base[b,f] = (1/N) * sum over columns with NO positive edge of Wh[b,t,f]
__global__ void base_kernel(const unsigned* __restrict__ Menc, const float* __restrict__ Wh,
                            float* __restrict__ base) {
    int bx = blockIdx.x;                 // BB*32 blocks
    int b = bx >> 5, chunk = bx & 31;
    int f = threadIdx.x & 63, ty = threadIdx.x >> 6;
    float acc = 0.f;
    int t0 = chunk * (NN / 32);
    for (int t = t0 + ty; t < t0 + NN / 32; t += 4)
        if (Menc[(b << 12) | t] == 0u) acc += Wh[(((long)b << 12) | t) * FOUT + f];
    __shared__ float red[4][64];
    red[ty][f] = acc;
    __syncthreads();
    if (ty == 0)
        atomicAdd(&base[(b << 6) | f],
                  (red[0][f] + red[1][f] + red[2][f] + red[3][f]) * (1.0f / NN));
}

// one wave per output row: out[b,s,:] = ELU( sum_t exp(as_s-M_t)/D_t * Wh[b,t,:] + base )
__global__ void gather_kernel(const int* __restrict__ deg, const int* __restrict__ csr,
                              const float* __restrict__ as_, const unsigned* __restrict__ Menc,
                              const float* __restrict__ D, const float* __restrict__ Wh,
                              const float* __restrict__ base, float* __restrict__ out) {
    int tid = threadIdx.x;
    int lane = tid & 63;
    int row = blockIdx.x * 4 + (tid >> 6);
    int b = row >> 12, s = row & 4095;
    int d = deg[row];                               // deduped count
    float as_s = as_[s];
    float acc = 0.f;
    const int* cr = csr + row * CAP;
    const float* Whb = Wh + (((long)b << 12) * FOUT);
    for (int j = 0; j < d; ++j) {
        int t = cr[j];                              // wave-uniform
        float M = dec_f32(Menc[(b << 12) | t]);
        float w = expf(as_s - M) / D[(b << 12) | t];
        acc += w * Whb[t * FOUT + lane];            // coalesced 256B gather
    }
    float x = acc + base[(b << 6) | lane];
    out[(long)row * FOUT + lane] = x > 0.f ? x : expm1f(x);
}

extern "C" void kernel_launch(void* const* d_in, const int* in_sizes, int n_in,
                              void* d_out, int out_size, void* d_ws, size_t ws_size,
                              hipStream_t stream) {
    const float* h  = (const float*)d_in[0];
    const int*   ei = (const int*)d_in[1];
    const float* W  = (const float*)d_in[2];
    const float* a  = (const float*)d_in[3];
    float* out = (float*)d_out;

    char* ws = (char*)d_ws;
    float*    Wh   = (float*)(ws);                       // 4 MiB
    int*      csr  = (int*)(ws + 4194304);               // 4 MiB (CAP=64)
    int*      deg  = (int*)(ws + 8388608);               // 64 KiB
    unsigned* Menc = (unsigned*)(ws + 8454144);          // 64 KiB
    float*    D    = (float*)(ws + 8519680);             // 64 KiB
    float*    as_  = (float*)(ws + 8585216);             // 16 KiB
    float*    at_  = (float*)(ws + 8601600);             // 16 KiB
    float*    base = (float*)(ws + 8617984);             // 1 KiB
    float*    Wa   = (float*)(ws + 8619008);             // 1 KiB

    init_kernel<<<64, 256, 0, stream>>>(W, a, deg, Menc, D, base, Wa);
    wh_kernel<<<BB * NN / 32, 256, 0, stream>>>(h, W, Wh);
    as_at_kernel<<<NN / 4, 256, 0, stream>>>(h, Wa, as_, at_);
    edge_kernel<<<(BB * EE) / 256, 256, 0, stream>>>(ei, as_, at_, Menc, deg, csr);
    dedup_denom_kernel<<<(BB * NN) / 4, 256, 0, stream>>>(deg, csr, as_, Menc, D);
    base_kernel<<<BB * 32, 256, 0, stream>>>(Menc, Wh, base);
    gather_kernel<<<(BB * NN) / 4, 256, 0, stream>>>(deg, csr, as_, Menc, D, Wh, base, out);
}